// Round 1
// baseline (251.436 us; speedup 1.0000x reference)
//
#include <hip/hip_runtime.h>

// RNN_arch_2: 16-step vanilla RNN, B=16384, D_IN=64, D_H=256, D_MID=64, D_OUT=4.
// Strategy: recurrence is independent per batch row -> 1 block per 64-row tile,
// block walks all 16 steps with h carried in LDS (f16). All matmuls via
// mfma_f32_16x16x32_f16 (fp32 accumulate). Weight B-fragments persist in
// registers across the whole t-loop (loaded once per block from global fp32).
// fp16 chosen over bf16 for accuracy: rel 2^-11 keeps recurrent error ~4e-3
// vs threshold 2e-2.

typedef _Float16 half8 __attribute__((ext_vector_type(8)));
typedef float floatx4 __attribute__((ext_vector_type(4)));

#define T_STEPS 16
#define BATCH   16384
#define HS      264   // h_lds row stride (f16): 528B -> +4 banks/row, <=2-way
#define MS      72    // mid_lds row stride (f16)

__device__ inline float fast_tanh(float x) {
    // tanh(x) = 1 - 2/(1+exp2(2*log2e*x)); saturates correctly at +-inf
    float t = __builtin_amdgcn_exp2f(x * 2.8853900817779268f);
    return 1.0f - 2.0f * __builtin_amdgcn_rcpf(t + 1.0f);
}

__device__ inline half8 cvt8(const float* __restrict__ p) {
    float4 a = ((const float4*)p)[0];
    float4 b = ((const float4*)p)[1];
    half8 h;
    h[0] = (_Float16)a.x; h[1] = (_Float16)a.y; h[2] = (_Float16)a.z; h[3] = (_Float16)a.w;
    h[4] = (_Float16)b.x; h[5] = (_Float16)b.y; h[6] = (_Float16)b.z; h[7] = (_Float16)b.w;
    return h;
}

__global__ __launch_bounds__(256, 1) void rnn_kernel(
    const float* __restrict__ x,   const float* __restrict__ hc1,
    const float* __restrict__ Wi,  const float* __restrict__ bi,
    const float* __restrict__ Wh,  const float* __restrict__ bh,
    const float* __restrict__ Wo,  const float* __restrict__ bo,
    const float* __restrict__ Wf,  const float* __restrict__ bf,
    float* __restrict__ out)
{
    __shared__ _Float16 h_lds[64 * HS];     // h tile, f16: [row][k]
    __shared__ _Float16 mid_lds[64 * MS];   // tanh(h2o) tile
    __shared__ float    biasPre[256];       // b_i2h + b_h2h
    __shared__ float    bo_lds[64];
    __shared__ _Float16 wfc_lds[4 * 64];
    __shared__ float    bfc_lds[4];

    const int tid  = threadIdx.x;
    const int w    = tid >> 6;        // wave 0..3 -> output col strip w*64
    const int lane = tid & 63;
    const int l16  = lane & 15;
    const int quad = lane >> 4;
    const int b0   = blockIdx.x * 64;

    // --- one-time LDS init ---
    biasPre[tid] = bi[tid] + bh[tid];
    if (tid < 64) bo_lds[tid] = bo[tid];
    wfc_lds[tid] = (_Float16)Wf[tid];
    if (tid < 4) bfc_lds[tid] = bf[tid];

    // stage hc1 -> h_lds (f16)
    {
        int r = tid >> 2, c0 = (tid & 3) * 64;
        const float4* src = (const float4*)&hc1[(size_t)(b0 + r) * 256 + c0];
        #pragma unroll
        for (int i = 0; i < 16; ++i) {
            float4 v = src[i];
            int c = c0 + i * 4;
            h_lds[r * HS + c + 0] = (_Float16)v.x;
            h_lds[r * HS + c + 1] = (_Float16)v.y;
            h_lds[r * HS + c + 2] = (_Float16)v.z;
            h_lds[r * HS + c + 3] = (_Float16)v.w;
        }
    }

    // --- persistent weight fragments (registers, loaded once) ---
    // B layout for mfma 16x16x32: n = lane&15, k = quad*8 + j  -> contiguous
    // 8 elems of W[n][k] (W stored [out][in] row-major = exactly [n][k]).
    half8 wcat[10][4];   // K=320 concat [Wi(k<64); Wh(k>=64)], 4 n-tiles/wave
    #pragma unroll
    for (int ks = 0; ks < 10; ++ks) {
        #pragma unroll
        for (int nt = 0; nt < 4; ++nt) {
            int j = w * 64 + nt * 16 + l16;
            const float* src = (ks < 2)
                ? (Wi + (size_t)j * 64  + ks * 32 + quad * 8)
                : (Wh + (size_t)j * 256 + (ks - 2) * 32 + quad * 8);
            wcat[ks][nt] = cvt8(src);
        }
    }
    half8 wof[8];        // W_h2o: wave covers 16 out-cols, K=256
    #pragma unroll
    for (int ks = 0; ks < 8; ++ks) {
        int j = w * 16 + l16;
        wof[ks] = cvt8(Wo + (size_t)j * 256 + ks * 32 + quad * 8);
    }

    __syncthreads();

    for (int t = 0; t < T_STEPS; ++t) {
        // x fragments straight from global (A layout: m=lane&15, k=quad*8+j)
        half8 afx[4][2];
        #pragma unroll
        for (int mt = 0; mt < 4; ++mt) {
            int m = mt * 16 + l16;
            const float* xr = x + ((size_t)t * BATCH + b0 + m) * 64;
            #pragma unroll
            for (int k2 = 0; k2 < 2; ++k2)
                afx[mt][k2] = cvt8(xr + k2 * 32 + quad * 8);
        }

        // ---- pre = [x|h] @ [Wi;Wh]^T : K=320, per-wave 64x64 out tile ----
        floatx4 acc[4][4];
        #pragma unroll
        for (int mt = 0; mt < 4; ++mt)
            #pragma unroll
            for (int nt = 0; nt < 4; ++nt)
                acc[mt][nt] = (floatx4){0.f, 0.f, 0.f, 0.f};

        #pragma unroll
        for (int ks = 0; ks < 10; ++ks) {
            half8 af[4];
            #pragma unroll
            for (int mt = 0; mt < 4; ++mt) {
                if (ks < 2) {
                    af[mt] = afx[mt][ks];
                } else {
                    int m = mt * 16 + l16;
                    af[mt] = *(const half8*)&h_lds[m * HS + (ks - 2) * 32 + quad * 8];
                }
            }
            #pragma unroll
            for (int mt = 0; mt < 4; ++mt)
                #pragma unroll
                for (int nt = 0; nt < 4; ++nt)
                    acc[mt][nt] = __builtin_amdgcn_mfma_f32_16x16x32_f16(
                        af[mt], wcat[ks][nt], acc[mt][nt], 0, 0, 0);
        }

        __syncthreads();   // all waves done READING old h

        // epilogue: h = tanh(pre + bias) -> h_lds (f16)
        // C layout: col = lane&15 (+tile), row = quad*4 + reg (+tile)
        #pragma unroll
        for (int nt = 0; nt < 4; ++nt) {
            int col = w * 64 + nt * 16 + l16;
            float bias = biasPre[col];
            #pragma unroll
            for (int mt = 0; mt < 4; ++mt) {
                #pragma unroll
                for (int r = 0; r < 4; ++r) {
                    int row = mt * 16 + quad * 4 + r;
                    h_lds[row * HS + col] = (_Float16)fast_tanh(acc[mt][nt][r] + bias);
                }
            }
        }

        __syncthreads();   // new h visible

        // ---- mid = tanh(h @ Wo^T + bo) : [64x64], wave covers 16 cols ----
        floatx4 acc2[4];
        #pragma unroll
        for (int mt = 0; mt < 4; ++mt) acc2[mt] = (floatx4){0.f, 0.f, 0.f, 0.f};
        #pragma unroll
        for (int ks = 0; ks < 8; ++ks) {
            #pragma unroll
            for (int mt = 0; mt < 4; ++mt) {
                int m = mt * 16 + l16;
                half8 af = *(const half8*)&h_lds[m * HS + ks * 32 + quad * 8];
                acc2[mt] = __builtin_amdgcn_mfma_f32_16x16x32_f16(
                    af, wof[ks], acc2[mt], 0, 0, 0);
            }
        }
        {
            int col = w * 16 + l16;
            float bias = bo_lds[col];
            #pragma unroll
            for (int mt = 0; mt < 4; ++mt)
                #pragma unroll
                for (int r = 0; r < 4; ++r) {
                    int row = mt * 16 + quad * 4 + r;
                    mid_lds[row * MS + col] = (_Float16)fast_tanh(acc2[mt][r] + bias);
                }
        }

        __syncthreads();   // mid visible

        // ---- out = mid @ Wfc^T + bfc : thread = (row, oc), 64x4 = 256 ----
        {
            int row = tid >> 2, oc = tid & 3;
            float s = bfc_lds[oc];
            #pragma unroll
            for (int k8 = 0; k8 < 64; k8 += 8) {
                half8 mv = *(const half8*)&mid_lds[row * MS + k8];
                half8 wv = *(const half8*)&wfc_lds[oc * 64 + k8];
                #pragma unroll
                for (int j = 0; j < 8; ++j)
                    s += (float)mv[j] * (float)wv[j];
            }
            out[((size_t)t * BATCH + b0 + row) * 4 + oc] = s;
        }
        // no barrier needed here: next write to mid/h is behind 2 barriers
    }

    // ---- h_final (fp32) at offset T*B*4 ----
    {
        int r = tid >> 2, c0 = (tid & 3) * 64;
        float4* dst = (float4*)&out[(size_t)T_STEPS * BATCH * 4 + (size_t)(b0 + r) * 256 + c0];
        #pragma unroll
        for (int i = 0; i < 16; ++i) {
            int c = c0 + i * 4;
            float4 v;
            v.x = (float)h_lds[r * HS + c + 0];
            v.y = (float)h_lds[r * HS + c + 1];
            v.z = (float)h_lds[r * HS + c + 2];
            v.w = (float)h_lds[r * HS + c + 3];
            dst[i] = v;
        }
    }
}

extern "C" void kernel_launch(void* const* d_in, const int* in_sizes, int n_in,
                              void* d_out, int out_size, void* d_ws, size_t ws_size,
                              hipStream_t stream) {
    const float* x   = (const float*)d_in[0];
    const float* hc1 = (const float*)d_in[1];
    const float* Wi  = (const float*)d_in[2];
    const float* bi  = (const float*)d_in[3];
    const float* Wh  = (const float*)d_in[4];
    const float* bh  = (const float*)d_in[5];
    const float* Wo  = (const float*)d_in[6];
    const float* bo  = (const float*)d_in[7];
    const float* Wf  = (const float*)d_in[8];
    const float* bf  = (const float*)d_in[9];

    rnn_kernel<<<256, 256, 0, stream>>>(x, hc1, Wi, bi, Wh, bh, Wo, bo, Wf, bf,
                                        (float*)d_out);
}

// Round 2
// 221.323 us; speedup vs baseline: 1.1361x; 1.1361x over previous
//
#include <hip/hip_runtime.h>

// RNN_arch_2: 16-step vanilla RNN, B=16384, D_IN=64, D_H=256, D_MID=64, D_OUT=4.
// R2: latency-bound at 11% occupancy (1 block/CU). VGPR 176 permits 2
// waves/SIMD, so split to 512 blocks x 32 rows -> 2 independent blocks/CU
// (8 waves/CU) to overlap barrier stalls and memory latency.
// Weights persist in registers (fp16 B-fragments, loaded once per block);
// h carried in LDS (f16); all matmuls via mfma_f32_16x16x32_f16.

typedef _Float16 half8 __attribute__((ext_vector_type(8)));
typedef float floatx4 __attribute__((ext_vector_type(4)));

#define T_STEPS  16
#define BATCH    16384
#define BLK_ROWS 32
#define HS       264   // h_lds row stride (f16): 528B -> 2-way bank alias, free
#define MS       72    // mid_lds row stride (f16)

__device__ inline float fast_tanh(float x) {
    // tanh(x) = 1 - 2/(1+exp2(2*log2e*x)); saturates correctly at +-inf
    float t = __builtin_amdgcn_exp2f(x * 2.8853900817779268f);
    return 1.0f - 2.0f * __builtin_amdgcn_rcpf(t + 1.0f);
}

__device__ inline half8 cvt8(const float* __restrict__ p) {
    float4 a = ((const float4*)p)[0];
    float4 b = ((const float4*)p)[1];
    half8 h;
    h[0] = (_Float16)a.x; h[1] = (_Float16)a.y; h[2] = (_Float16)a.z; h[3] = (_Float16)a.w;
    h[4] = (_Float16)b.x; h[5] = (_Float16)b.y; h[6] = (_Float16)b.z; h[7] = (_Float16)b.w;
    return h;
}

__global__ __launch_bounds__(256, 2) void rnn_kernel(
    const float* __restrict__ x,   const float* __restrict__ hc1,
    const float* __restrict__ Wi,  const float* __restrict__ bi,
    const float* __restrict__ Wh,  const float* __restrict__ bh,
    const float* __restrict__ Wo,  const float* __restrict__ bo,
    const float* __restrict__ Wf,  const float* __restrict__ bf,
    float* __restrict__ out)
{
    __shared__ _Float16 h_lds[BLK_ROWS * HS];     // h tile, f16: [row][k]
    __shared__ _Float16 mid_lds[BLK_ROWS * MS];   // tanh(h2o) tile
    __shared__ float    biasPre[256];             // b_i2h + b_h2h
    __shared__ float    bo_lds[64];
    __shared__ _Float16 wfc_lds[4 * 64];
    __shared__ float    bfc_lds[4];

    const int tid  = threadIdx.x;
    const int w    = tid >> 6;        // wave 0..3 -> output col strip w*64
    const int lane = tid & 63;
    const int l16  = lane & 15;
    const int quad = lane >> 4;
    const int b0   = blockIdx.x * BLK_ROWS;

    // --- one-time LDS init ---
    biasPre[tid] = bi[tid] + bh[tid];
    if (tid < 64) bo_lds[tid] = bo[tid];
    wfc_lds[tid] = (_Float16)Wf[tid];
    if (tid < 4) bfc_lds[tid] = bf[tid];

    // stage hc1 -> h_lds (f16): 32 rows x 256 cols, 8 threads/row
    {
        int r = tid >> 3, c0 = (tid & 7) * 32;
        const float4* src = (const float4*)&hc1[(size_t)(b0 + r) * 256 + c0];
        #pragma unroll
        for (int i = 0; i < 8; ++i) {
            float4 v = src[i];
            int c = c0 + i * 4;
            h_lds[r * HS + c + 0] = (_Float16)v.x;
            h_lds[r * HS + c + 1] = (_Float16)v.y;
            h_lds[r * HS + c + 2] = (_Float16)v.z;
            h_lds[r * HS + c + 3] = (_Float16)v.w;
        }
    }

    // --- persistent weight fragments (registers, loaded once) ---
    // B layout for mfma 16x16x32: n = lane&15, k = quad*8 + j  -> contiguous
    // 8 elems of W[n][k] (W stored [out][in] row-major = exactly [n][k]).
    half8 wcat[10][4];   // K=320 concat [Wi(k<64); Wh(k>=64)], 4 n-tiles/wave
    #pragma unroll
    for (int ks = 0; ks < 10; ++ks) {
        #pragma unroll
        for (int nt = 0; nt < 4; ++nt) {
            int j = w * 64 + nt * 16 + l16;
            const float* src = (ks < 2)
                ? (Wi + (size_t)j * 64  + ks * 32 + quad * 8)
                : (Wh + (size_t)j * 256 + (ks - 2) * 32 + quad * 8);
            wcat[ks][nt] = cvt8(src);
        }
    }
    half8 wof[8];        // W_h2o: wave covers 16 out-cols, K=256
    #pragma unroll
    for (int ks = 0; ks < 8; ++ks) {
        int j = w * 16 + l16;
        wof[ks] = cvt8(Wo + (size_t)j * 256 + ks * 32 + quad * 8);
    }

    __syncthreads();

    for (int t = 0; t < T_STEPS; ++t) {
        // x fragments straight from global (A layout: m=lane&15, k=quad*8+j)
        half8 afx[2][2];
        #pragma unroll
        for (int mt = 0; mt < 2; ++mt) {
            int m = mt * 16 + l16;
            const float* xr = x + ((size_t)t * BATCH + b0 + m) * 64;
            #pragma unroll
            for (int k2 = 0; k2 < 2; ++k2)
                afx[mt][k2] = cvt8(xr + k2 * 32 + quad * 8);
        }

        // ---- pre = [x|h] @ [Wi;Wh]^T : K=320, per-wave 32x64 out tile ----
        floatx4 acc[2][4];
        #pragma unroll
        for (int mt = 0; mt < 2; ++mt)
            #pragma unroll
            for (int nt = 0; nt < 4; ++nt)
                acc[mt][nt] = (floatx4){0.f, 0.f, 0.f, 0.f};

        #pragma unroll
        for (int ks = 0; ks < 10; ++ks) {
            half8 af[2];
            #pragma unroll
            for (int mt = 0; mt < 2; ++mt) {
                if (ks < 2) {
                    af[mt] = afx[mt][ks];
                } else {
                    int m = mt * 16 + l16;
                    af[mt] = *(const half8*)&h_lds[m * HS + (ks - 2) * 32 + quad * 8];
                }
            }
            #pragma unroll
            for (int mt = 0; mt < 2; ++mt)
                #pragma unroll
                for (int nt = 0; nt < 4; ++nt)
                    acc[mt][nt] = __builtin_amdgcn_mfma_f32_16x16x32_f16(
                        af[mt], wcat[ks][nt], acc[mt][nt], 0, 0, 0);
        }

        __syncthreads();   // all waves done READING old h

        // epilogue: h = tanh(pre + bias) -> h_lds (f16)
        // C layout: col = lane&15 (+tile), row = quad*4 + reg (+tile)
        #pragma unroll
        for (int nt = 0; nt < 4; ++nt) {
            int col = w * 64 + nt * 16 + l16;
            float bias = biasPre[col];
            #pragma unroll
            for (int mt = 0; mt < 2; ++mt) {
                #pragma unroll
                for (int r = 0; r < 4; ++r) {
                    int row = mt * 16 + quad * 4 + r;
                    h_lds[row * HS + col] = (_Float16)fast_tanh(acc[mt][nt][r] + bias);
                }
            }
        }

        __syncthreads();   // new h visible

        // ---- mid = tanh(h @ Wo^T + bo) : [32x64], wave covers 16 cols ----
        floatx4 acc2[2];
        #pragma unroll
        for (int mt = 0; mt < 2; ++mt) acc2[mt] = (floatx4){0.f, 0.f, 0.f, 0.f};
        #pragma unroll
        for (int ks = 0; ks < 8; ++ks) {
            #pragma unroll
            for (int mt = 0; mt < 2; ++mt) {
                int m = mt * 16 + l16;
                half8 af = *(const half8*)&h_lds[m * HS + ks * 32 + quad * 8];
                acc2[mt] = __builtin_amdgcn_mfma_f32_16x16x32_f16(
                    af, wof[ks], acc2[mt], 0, 0, 0);
            }
        }
        {
            int col = w * 16 + l16;
            float bias = bo_lds[col];
            #pragma unroll
            for (int mt = 0; mt < 2; ++mt)
                #pragma unroll
                for (int r = 0; r < 4; ++r) {
                    int row = mt * 16 + quad * 4 + r;
                    mid_lds[row * MS + col] = (_Float16)fast_tanh(acc2[mt][r] + bias);
                }
        }

        __syncthreads();   // mid visible

        // ---- out = mid @ Wfc^T + bfc : thread = (row, oc), 32x4 = 128 ----
        if (tid < 128) {
            int row = tid >> 2, oc = tid & 3;
            float s = bfc_lds[oc];
            #pragma unroll
            for (int k8 = 0; k8 < 64; k8 += 8) {
                half8 mv = *(const half8*)&mid_lds[row * MS + k8];
                half8 wv = *(const half8*)&wfc_lds[oc * 64 + k8];
                #pragma unroll
                for (int j = 0; j < 8; ++j)
                    s += (float)mv[j] * (float)wv[j];
            }
            out[((size_t)t * BATCH + b0 + row) * 4 + oc] = s;
        }
        // no barrier needed here: next write to mid/h is behind 2 barriers
    }

    // ---- h_final (fp32) at offset T*B*4 ----
    {
        int r = tid >> 3, c0 = (tid & 7) * 32;
        float4* dst = (float4*)&out[(size_t)T_STEPS * BATCH * 4 + (size_t)(b0 + r) * 256 + c0];
        #pragma unroll
        for (int i = 0; i < 8; ++i) {
            int c = c0 + i * 4;
            float4 v;
            v.x = (float)h_lds[r * HS + c + 0];
            v.y = (float)h_lds[r * HS + c + 1];
            v.z = (float)h_lds[r * HS + c + 2];
            v.w = (float)h_lds[r * HS + c + 3];
            dst[i] = v;
        }
    }
}

extern "C" void kernel_launch(void* const* d_in, const int* in_sizes, int n_in,
                              void* d_out, int out_size, void* d_ws, size_t ws_size,
                              hipStream_t stream) {
    const float* x   = (const float*)d_in[0];
    const float* hc1 = (const float*)d_in[1];
    const float* Wi  = (const float*)d_in[2];
    const float* bi  = (const float*)d_in[3];
    const float* Wh  = (const float*)d_in[4];
    const float* bh  = (const float*)d_in[5];
    const float* Wo  = (const float*)d_in[6];
    const float* bo  = (const float*)d_in[7];
    const float* Wf  = (const float*)d_in[8];
    const float* bf  = (const float*)d_in[9];

    rnn_kernel<<<BATCH / BLK_ROWS, 256, 0, stream>>>(
        x, hc1, Wi, bi, Wh, bh, Wo, bo, Wf, bf, (float*)d_out);
}